// Round 3
// baseline (996.758 us; speedup 1.0000x reference)
//
#include <hip/hip_runtime.h>
#include <stdint.h>

#define DMODEL 2048
#define NHEADS 16
#define HD     128
#define BATCH  4
#define SEQ    2048
#define MROWS  (BATCH*SEQ)   // 8192

typedef __attribute__((ext_vector_type(8))) short short8;
typedef __attribute__((ext_vector_type(4))) float f32x4;

__device__ __forceinline__ unsigned short f2bf(float f) {
  uint32_t u = __float_as_uint(f);
  u += 0x7FFFu + ((u >> 16) & 1u);
  return (unsigned short)(u >> 16);
}
__device__ __forceinline__ float bf2f(unsigned short s) {
  return __uint_as_float(((uint32_t)s) << 16);
}

// ---------------- fp32 -> bf16 conversion (vectorized) ----------------
__global__ __launch_bounds__(256) void cvt_f32_bf16(
    const float* __restrict__ src, unsigned short* __restrict__ dst, int n4) {
  int i = blockIdx.x * 256 + threadIdx.x;
  if (i >= n4) return;
  float4 f = ((const float4*)src)[i];
  ushort4 o;
  o.x = f2bf(f.x); o.y = f2bf(f.y); o.z = f2bf(f.z); o.w = f2bf(f.w);
  ((ushort4*)dst)[i] = o;
}

// ---------------- RoPE cos/sin table: [S][64] fp32 ----------------
__global__ __launch_bounds__(256) void rope_table(
    float* __restrict__ ct, float* __restrict__ st) {
  int idx = blockIdx.x * 256 + threadIdx.x;      // S*64 = 131072 exact
  int s = idx >> 6, i = idx & 63;
  // inv_freq = 10000^(-i/64) = exp2(-i/64 * log2(10000))
  float invf = exp2f(-(float)i * (13.287712379549449f / 64.0f));
  float a = (float)s * invf;
  ct[idx] = cosf(a);
  st[idx] = sinf(a);
}

// ---------------- RoPE apply in place on bf16 (B,S,H,hd) ----------------
__global__ __launch_bounds__(256) void rope_apply(
    unsigned short* __restrict__ X, const float* __restrict__ ct,
    const float* __restrict__ st) {
  int idx = blockIdx.x * 256 + threadIdx.x;  // total 2,097,152 (exact grid)
  int i0  = (idx & 15) * 4;                  // pair index 0..63 in quads
  int h   = (idx >> 4) & 15;
  int row = idx >> 8;                        // b*S + s  (0..8191)
  int s   = row & (SEQ - 1);
  size_t base = (size_t)row * DMODEL + h * HD + i0;
  ushort4 lo = *(const ushort4*)&X[base];
  ushort4 hi = *(const ushort4*)&X[base + 64];
  float4 c  = *(const float4*)&ct[s * 64 + i0];
  float4 sn = *(const float4*)&st[s * 64 + i0];
  ushort4 olo, ohi;
  olo.x = f2bf(bf2f(lo.x) * c.x - bf2f(hi.x) * sn.x);
  olo.y = f2bf(bf2f(lo.y) * c.y - bf2f(hi.y) * sn.y);
  olo.z = f2bf(bf2f(lo.z) * c.z - bf2f(hi.z) * sn.z);
  olo.w = f2bf(bf2f(lo.w) * c.w - bf2f(hi.w) * sn.w);
  ohi.x = f2bf(bf2f(hi.x) * c.x + bf2f(lo.x) * sn.x);
  ohi.y = f2bf(bf2f(hi.y) * c.y + bf2f(lo.y) * sn.y);
  ohi.z = f2bf(bf2f(hi.z) * c.z + bf2f(lo.z) * sn.z);
  ohi.w = f2bf(bf2f(hi.w) * c.w + bf2f(lo.w) * sn.w);
  *(ushort4*)&X[base]      = olo;
  *(ushort4*)&X[base + 64] = ohi;
}

// ---------------- NT GEMM: C[m,n] = sum_k A[m,k]*B[n,k], bf16 in ----------------
// 128x128 tile, BK=64, 256 threads (4 waves, 2x2), global_load_lds staging.
template<bool OUT_BF16>
__global__ __launch_bounds__(256) void gemm_nt(
    const unsigned short* __restrict__ A,
    const unsigned short* __restrict__ B0, const unsigned short* __restrict__ B1,
    const unsigned short* __restrict__ B2,
    void* __restrict__ C0, void* __restrict__ C1, void* __restrict__ C2,
    int K, int N) {
  const unsigned short* Bm = (blockIdx.z == 0) ? B0 : (blockIdx.z == 1) ? B1 : B2;
  void* Cm = (blockIdx.z == 0) ? C0 : (blockIdx.z == 1) ? C1 : C2;
  const int m0 = blockIdx.x * 128, n0 = blockIdx.y * 128;
  __shared__ unsigned short As[128 * 64];
  __shared__ unsigned short Bs[128 * 64];
  const int t = threadIdx.x, w = t >> 6, lane = t & 63;
  const int wr = w >> 1, wc = w & 1, g = lane >> 4, cl = lane & 15;

  f32x4 acc[4][4];
  const f32x4 zero = {0.f, 0.f, 0.f, 0.f};
#pragma unroll
  for (int mi = 0; mi < 4; ++mi)
#pragma unroll
    for (int ni = 0; ni < 4; ++ni) acc[mi][ni] = zero;

  for (int k0 = 0; k0 < K; k0 += 64) {
    __syncthreads();
#pragma unroll
    for (int i = 0; i < 4; ++i) {
      int f16 = (w * 4 + i) * 64 + lane;     // 16B chunk id
      int row = f16 >> 3, col = (f16 & 7) * 8;
      __builtin_amdgcn_global_load_lds(
          (const __attribute__((address_space(1))) void*)(A + (size_t)(m0 + row) * K + k0 + col),
          (__attribute__((address_space(3))) void*)(&As[(size_t)f16 * 8]), 16, 0, 0);
      __builtin_amdgcn_global_load_lds(
          (const __attribute__((address_space(1))) void*)(Bm + (size_t)(n0 + row) * K + k0 + col),
          (__attribute__((address_space(3))) void*)(&Bs[(size_t)f16 * 8]), 16, 0, 0);
    }
    __syncthreads();
#pragma unroll
    for (int kk = 0; kk < 2; ++kk) {
      short8 a[4], b[4];
#pragma unroll
      for (int mi = 0; mi < 4; ++mi)
        a[mi] = *(const short8*)&As[(wr * 64 + mi * 16 + cl) * 64 + kk * 32 + g * 8];
#pragma unroll
      for (int ni = 0; ni < 4; ++ni)
        b[ni] = *(const short8*)&Bs[(wc * 64 + ni * 16 + cl) * 64 + kk * 32 + g * 8];
#pragma unroll
      for (int mi = 0; mi < 4; ++mi)
#pragma unroll
        for (int ni = 0; ni < 4; ++ni)
          acc[mi][ni] = __builtin_amdgcn_mfma_f32_16x16x32_bf16(a[mi], b[ni], acc[mi][ni], 0, 0, 0);
    }
  }
  // epilogue: C/D layout col=lane&15, row=(lane>>4)*4+r
#pragma unroll
  for (int mi = 0; mi < 4; ++mi)
#pragma unroll
    for (int ni = 0; ni < 4; ++ni) {
      int row = m0 + wr * 64 + mi * 16 + g * 4;
      int col = n0 + wc * 64 + ni * 16 + cl;
#pragma unroll
      for (int r = 0; r < 4; ++r) {
        float v = acc[mi][ni][r];
        if (OUT_BF16)
          ((unsigned short*)Cm)[(size_t)(row + r) * N + col] = f2bf(v);
        else
          ((float*)Cm)[(size_t)(row + r) * N + col] = v;
      }
    }
}

// ---------------- causal flash attention, bf16 ----------------
// grid (S/64, B*H); 256 threads = 4 waves x 16 q-rows; KVB=64.
__global__ __launch_bounds__(256) void attn_kernel(
    const unsigned short* __restrict__ Q, const unsigned short* __restrict__ Kk,
    const unsigned short* __restrict__ V, unsigned short* __restrict__ O) {
  const int qt = (int)gridDim.x - 1 - (int)blockIdx.x;  // big tiles dispatched first
  const int q0 = qt * 64;
  const int bh = blockIdx.y, b = bh >> 4, h = bh & 15;
  const size_t base = (size_t)b * SEQ * DMODEL + (size_t)h * HD;

  __shared__ unsigned short Ks[64 * 136];   // K tile, padded rows (read 2-way free)
  __shared__ unsigned short Vt[128 * 72];   // V transposed [hd][kv], padded
  __shared__ unsigned short Pl[4][16 * 72]; // per-wave P tile [q][kv], padded

  const int t = threadIdx.x, w = t >> 6, lane = t & 63;
  const int g = lane >> 4, cl = lane & 15;

  // Q fragments: wave w owns q rows q0 + w*16 + [0,16)
  short8 qf[4];
  {
    const unsigned short* qrow = Q + base + (size_t)(q0 + w * 16 + cl) * DMODEL;
#pragma unroll
    for (int kk = 0; kk < 4; ++kk) qf[kk] = *(const short8*)(qrow + kk * 32 + g * 8);
  }

  f32x4 o_acc[8];
  const f32x4 zero = {0.f, 0.f, 0.f, 0.f};
#pragma unroll
  for (int n = 0; n < 8; ++n) o_acc[n] = zero;
  float m_run[4], l_run[4];
#pragma unroll
  for (int r = 0; r < 4; ++r) { m_run[r] = -INFINITY; l_run[r] = 0.f; }

  const int my_qmax = q0 + w * 16 + 15;
  const int ntiles = qt + 1;
  constexpr float SC = 0.08838834764831845f * 1.4426950408889634f;  // 1/sqrt(128)*log2(e)

  for (int tkv = 0; tkv < ntiles; ++tkv) {
    const int kv0 = tkv * 64;
    __syncthreads();
    // stage K: thread (pass p): row = p*16 + t>>4, 8 elems at (t&15)*8 -> coalesced
#pragma unroll
    for (int p = 0; p < 4; ++p) {
      int row = p * 16 + (t >> 4), c8 = t & 15;
      const unsigned short* src = Kk + base + (size_t)(kv0 + row) * DMODEL + c8 * 8;
      *(short8*)&Ks[row * 136 + c8 * 8] = *(const short8*)src;
    }
    // stage V transposed: kv = t&63 (lanes consecutive kv -> conflict-free writes)
#pragma unroll
    for (int p = 0; p < 4; ++p) {
      int kv = t & 63, h0 = ((t >> 6) + p * 4) * 8;
      const unsigned short* src = V + base + (size_t)(kv0 + kv) * DMODEL + h0;
      short8 vv = *(const short8*)src;
#pragma unroll
      for (int e = 0; e < 8; ++e) Vt[(h0 + e) * 72 + kv] = (unsigned short)vv[e];
    }
    __syncthreads();

    if (kv0 <= my_qmax) {
      // QK^T: S[q(16) x kv(64)] per wave
      float sm[4][4];
#pragma unroll
      for (int c = 0; c < 4; ++c) {
        f32x4 sa = zero;
#pragma unroll
        for (int kk = 0; kk < 4; ++kk) {
          short8 kf = *(const short8*)&Ks[(c * 16 + cl) * 136 + kk * 32 + g * 8];
          sa = __builtin_amdgcn_mfma_f32_16x16x32_bf16(qf[kk], kf, sa, 0, 0, 0);
        }
#pragma unroll
        for (int r = 0; r < 4; ++r) {
          float sv = sa[r] * SC;
          int kvg = kv0 + c * 16 + cl;
          int qg  = q0 + w * 16 + g * 4 + r;
          sm[c][r] = (kvg > qg) ? -INFINITY : sv;
        }
      }
      // online softmax (per 16-lane group; rows = g*4+r)
      float alpha[4];
#pragma unroll
      for (int r = 0; r < 4; ++r) {
        float mx = fmaxf(fmaxf(sm[0][r], sm[1][r]), fmaxf(sm[2][r], sm[3][r]));
#pragma unroll
        for (int msk = 8; msk >= 1; msk >>= 1) mx = fmaxf(mx, __shfl_xor(mx, msk, 16));
        float mnew = fmaxf(m_run[r], mx);
        alpha[r] = exp2f(m_run[r] - mnew);   // first tile: exp2(-inf)=0
        m_run[r] = mnew;
        float s0 = 0.f;
#pragma unroll
        for (int c = 0; c < 4; ++c) {
          float p = exp2f(sm[c][r] - mnew);
          sm[c][r] = p;
          s0 += p;
        }
#pragma unroll
        for (int msk = 8; msk >= 1; msk >>= 1) s0 += __shfl_xor(s0, msk, 16);
        l_run[r] = l_run[r] * alpha[r] + s0;
      }
#pragma unroll
      for (int n = 0; n < 8; ++n)
#pragma unroll
        for (int r = 0; r < 4; ++r) o_acc[n][r] *= alpha[r];
      // P -> LDS (bf16), rows = q, cols = kv
#pragma unroll
      for (int c = 0; c < 4; ++c)
#pragma unroll
        for (int r = 0; r < 4; ++r)
          Pl[w][(g * 4 + r) * 72 + c * 16 + cl] = f2bf(sm[c][r]);
      // PV: out[q x hd] += P[q x kv] * V[kv x hd]
#pragma unroll
      for (int kk = 0; kk < 2; ++kk) {
        short8 pa = *(const short8*)&Pl[w][cl * 72 + kk * 32 + g * 8];
#pragma unroll
        for (int n = 0; n < 8; ++n) {
          short8 vf = *(const short8*)&Vt[(n * 16 + cl) * 72 + kk * 32 + g * 8];
          o_acc[n] = __builtin_amdgcn_mfma_f32_16x16x32_bf16(pa, vf, o_acc[n], 0, 0, 0);
        }
      }
    }
  }
  // epilogue: O[q][hd] = acc / l
  {
    const size_t obase = base + (size_t)(q0 + w * 16) * DMODEL;
#pragma unroll
    for (int r = 0; r < 4; ++r) {
      float inv = 1.0f / l_run[r];
      int qrow = g * 4 + r;
#pragma unroll
      for (int n = 0; n < 8; ++n)
        O[obase + (size_t)qrow * DMODEL + n * 16 + cl] = f2bf(o_acc[n][r] * inv);
    }
  }
}

// ---------------- launch ----------------
extern "C" void kernel_launch(void* const* d_in, const int* in_sizes, int n_in,
                              void* d_out, int out_size, void* d_ws, size_t ws_size,
                              hipStream_t stream) {
  const float* x  = (const float*)d_in[0];
  const float* Wq = (const float*)d_in[1];
  const float* Wk = (const float*)d_in[2];
  const float* Wv = (const float*)d_in[3];
  const float* Wo = (const float*)d_in[4];
  float* out = (float*)d_out;

  unsigned short* wsb = (unsigned short*)d_ws;
  const size_t XN = (size_t)MROWS * DMODEL;      // 16,777,216
  const size_t WN = (size_t)DMODEL * DMODEL;     // 4,194,304
  unsigned short* xb  = wsb;                     // bf16 x
  unsigned short* wqb = xb  + XN;
  unsigned short* wkb = wqb + WN;
  unsigned short* wvb = wkb + WN;
  unsigned short* wob = wvb + WN;
  unsigned short* qb  = wob + WN;
  unsigned short* kb  = qb  + XN;
  unsigned short* vb  = kb  + XN;
  unsigned short* aob = vb  + XN;
  float* cost = (float*)(aob + XN);
  float* sint = cost + (size_t)SEQ * 64;

  // 1. convert inputs to bf16
  cvt_f32_bf16<<<(int)(XN / 4 / 256), 256, 0, stream>>>(x,  xb,  (int)(XN / 4));
  cvt_f32_bf16<<<(int)(WN / 4 / 256), 256, 0, stream>>>(Wq, wqb, (int)(WN / 4));
  cvt_f32_bf16<<<(int)(WN / 4 / 256), 256, 0, stream>>>(Wk, wkb, (int)(WN / 4));
  cvt_f32_bf16<<<(int)(WN / 4 / 256), 256, 0, stream>>>(Wv, wvb, (int)(WN / 4));
  cvt_f32_bf16<<<(int)(WN / 4 / 256), 256, 0, stream>>>(Wo, wob, (int)(WN / 4));

  // 2. RoPE table
  rope_table<<<(SEQ * 64) / 256, 256, 0, stream>>>(cost, sint);

  // 3. QKV projections (fused launch via z)
  gemm_nt<true><<<dim3(MROWS / 128, DMODEL / 128, 3), 256, 0, stream>>>(
      xb, wqb, wkb, wvb, (void*)qb, (void*)kb, (void*)vb, DMODEL, DMODEL);

  // 4. RoPE on q, k
  rope_apply<<<(MROWS * NHEADS * 16) / 256, 256, 0, stream>>>(qb, cost, sint);
  rope_apply<<<(MROWS * NHEADS * 16) / 256, 256, 0, stream>>>(kb, cost, sint);

  // 5. causal flash attention
  attn_kernel<<<dim3(SEQ / 64, BATCH * NHEADS), 256, 0, stream>>>(qb, kb, vb, aob);

  // 6. output projection (fp32 out)
  gemm_nt<false><<<dim3(MROWS / 128, DMODEL / 128, 1), 256, 0, stream>>>(
      aob, wob, wob, wob, (void*)out, (void*)out, (void*)out, DMODEL, DMODEL);
}

// Round 5
// 957.250 us; speedup vs baseline: 1.0413x; 1.0413x over previous
//
#include <hip/hip_runtime.h>
#include <stdint.h>

#define DMODEL 2048
#define NHEADS 16
#define HD     128
#define BATCH  4
#define SEQ    2048
#define MROWS  (BATCH*SEQ)   // 8192

typedef __attribute__((ext_vector_type(8))) short short8;
typedef __attribute__((ext_vector_type(4))) float f32x4;

__device__ __forceinline__ unsigned short f2bf(float f) {
  uint32_t u = __float_as_uint(f);
  u += 0x7FFFu + ((u >> 16) & 1u);
  return (unsigned short)(u >> 16);
}
__device__ __forceinline__ float bf2f(unsigned short s) {
  return __uint_as_float(((uint32_t)s) << 16);
}

// ---------------- fp32 -> bf16 conversion (vectorized) ----------------
__global__ __launch_bounds__(256) void cvt_f32_bf16(
    const float* __restrict__ src, unsigned short* __restrict__ dst, int n4) {
  int i = blockIdx.x * 256 + threadIdx.x;
  if (i >= n4) return;
  float4 f = ((const float4*)src)[i];
  ushort4 o;
  o.x = f2bf(f.x); o.y = f2bf(f.y); o.z = f2bf(f.z); o.w = f2bf(f.w);
  ((ushort4*)dst)[i] = o;
}

// ---------------- RoPE cos/sin table: [S][64] fp32 ----------------
__global__ __launch_bounds__(256) void rope_table(
    float* __restrict__ ct, float* __restrict__ st) {
  int idx = blockIdx.x * 256 + threadIdx.x;      // S*64 = 131072 exact
  int s = idx >> 6, i = idx & 63;
  float invf = exp2f(-(float)i * (13.287712379549449f / 64.0f));
  float a = (float)s * invf;
  ct[idx] = cosf(a);
  st[idx] = sinf(a);
}

// ---------------- RoPE apply in place on bf16 (B,S,H,hd) ----------------
__global__ __launch_bounds__(256) void rope_apply(
    unsigned short* __restrict__ X, const float* __restrict__ ct,
    const float* __restrict__ st) {
  int idx = blockIdx.x * 256 + threadIdx.x;  // total 2,097,152 (exact grid)
  int i0  = (idx & 15) * 4;
  int h   = (idx >> 4) & 15;
  int row = idx >> 8;
  int s   = row & (SEQ - 1);
  size_t base = (size_t)row * DMODEL + h * HD + i0;
  ushort4 lo = *(const ushort4*)&X[base];
  ushort4 hi = *(const ushort4*)&X[base + 64];
  float4 c  = *(const float4*)&ct[s * 64 + i0];
  float4 sn = *(const float4*)&st[s * 64 + i0];
  ushort4 olo, ohi;
  olo.x = f2bf(bf2f(lo.x) * c.x - bf2f(hi.x) * sn.x);
  olo.y = f2bf(bf2f(lo.y) * c.y - bf2f(hi.y) * sn.y);
  olo.z = f2bf(bf2f(lo.z) * c.z - bf2f(hi.z) * sn.z);
  olo.w = f2bf(bf2f(lo.w) * c.w - bf2f(hi.w) * sn.w);
  ohi.x = f2bf(bf2f(hi.x) * c.x + bf2f(lo.x) * sn.x);
  ohi.y = f2bf(bf2f(hi.y) * c.y + bf2f(lo.y) * sn.y);
  ohi.z = f2bf(bf2f(hi.z) * c.z + bf2f(lo.z) * sn.z);
  ohi.w = f2bf(bf2f(hi.w) * c.w + bf2f(lo.w) * sn.w);
  *(ushort4*)&X[base]      = olo;
  *(ushort4*)&X[base + 64] = ohi;
}

// ---------------- NT GEMM: C[m,n] = sum_k A[m,k]*B[n,k], bf16 in ----------------
template<bool OUT_BF16>
__global__ __launch_bounds__(256) void gemm_nt(
    const unsigned short* __restrict__ A,
    const unsigned short* __restrict__ B0, const unsigned short* __restrict__ B1,
    const unsigned short* __restrict__ B2,
    void* __restrict__ C0, void* __restrict__ C1, void* __restrict__ C2,
    int K, int N) {
  const unsigned short* Bm = (blockIdx.z == 0) ? B0 : (blockIdx.z == 1) ? B1 : B2;
  void* Cm = (blockIdx.z == 0) ? C0 : (blockIdx.z == 1) ? C1 : C2;
  const int m0 = blockIdx.x * 128, n0 = blockIdx.y * 128;
  __shared__ unsigned short As[128 * 64];
  __shared__ unsigned short Bs[128 * 64];
  const int t = threadIdx.x, w = t >> 6, lane = t & 63;
  const int wr = w >> 1, wc = w & 1, g = lane >> 4, cl = lane & 15;

  f32x4 acc[4][4];
  const f32x4 zero = {0.f, 0.f, 0.f, 0.f};
#pragma unroll
  for (int mi = 0; mi < 4; ++mi)
#pragma unroll
    for (int ni = 0; ni < 4; ++ni) acc[mi][ni] = zero;

  for (int k0 = 0; k0 < K; k0 += 64) {
    __syncthreads();
#pragma unroll
    for (int i = 0; i < 4; ++i) {
      int f16 = (w * 4 + i) * 64 + lane;     // 16B chunk id
      int row = f16 >> 3, col = (f16 & 7) * 8;
      __builtin_amdgcn_global_load_lds(
          (const __attribute__((address_space(1))) void*)(A + (size_t)(m0 + row) * K + k0 + col),
          (__attribute__((address_space(3))) void*)(&As[(size_t)f16 * 8]), 16, 0, 0);
      __builtin_amdgcn_global_load_lds(
          (const __attribute__((address_space(1))) void*)(Bm + (size_t)(n0 + row) * K + k0 + col),
          (__attribute__((address_space(3))) void*)(&Bs[(size_t)f16 * 8]), 16, 0, 0);
    }
    __syncthreads();
#pragma unroll
    for (int kk = 0; kk < 2; ++kk) {
      short8 a[4], b[4];
#pragma unroll
      for (int mi = 0; mi < 4; ++mi)
        a[mi] = *(const short8*)&As[(wr * 64 + mi * 16 + cl) * 64 + kk * 32 + g * 8];
#pragma unroll
      for (int ni = 0; ni < 4; ++ni)
        b[ni] = *(const short8*)&Bs[(wc * 64 + ni * 16 + cl) * 64 + kk * 32 + g * 8];
#pragma unroll
      for (int mi = 0; mi < 4; ++mi)
#pragma unroll
        for (int ni = 0; ni < 4; ++ni)
          acc[mi][ni] = __builtin_amdgcn_mfma_f32_16x16x32_bf16(a[mi], b[ni], acc[mi][ni], 0, 0, 0);
    }
  }
#pragma unroll
  for (int mi = 0; mi < 4; ++mi)
#pragma unroll
    for (int ni = 0; ni < 4; ++ni) {
      int row = m0 + wr * 64 + mi * 16 + g * 4;
      int col = n0 + wc * 64 + ni * 16 + cl;
#pragma unroll
      for (int r = 0; r < 4; ++r) {
        float v = acc[mi][ni][r];
        if (OUT_BF16)
          ((unsigned short*)Cm)[(size_t)(row + r) * N + col] = f2bf(v);
        else
          ((float*)Cm)[(size_t)(row + r) * N + col] = v;
      }
    }
}

// ---------------- V transpose: [b][s][h][d] -> [bh][d][s] ----------------
// grid (SEQ/128, B*H), 256 threads. LDS-tiled 128x128.
__global__ __launch_bounds__(256) void transpose_v(
    const unsigned short* __restrict__ Vin, unsigned short* __restrict__ Vt) {
  const int s0 = blockIdx.x * 128;
  const int bh = blockIdx.y, b = bh >> 4, h = bh & 15;
  __shared__ unsigned short Ts[128 * 136];   // pad 8 elems: out-reads 2-way (free)
  const int t = threadIdx.x;
  const unsigned short* src = Vin + ((size_t)b * SEQ + s0) * DMODEL + h * HD;
#pragma unroll
  for (int p = 0; p < 8; ++p) {
    int task = t + p * 256;                  // 2048 chunks of 16B
    int r = task >> 4, ch = task & 15;
    *(short8*)&Ts[r * 136 + ch * 8] = *(const short8*)(src + (size_t)r * DMODEL + ch * 8);
  }
  __syncthreads();
  unsigned short* dst = Vt + ((size_t)bh << 18) + s0;
#pragma unroll
  for (int p = 0; p < 2; ++p) {
    int task = t + p * 256;                  // 512 tasks: (d, csq)
    int d = task & 127, csq = task >> 7;     // lanes: consecutive d
#pragma unroll
    for (int j = 0; j < 4; ++j) {            // 4x16B consecutive => 64B/thread
      short8 v;
#pragma unroll
      for (int e = 0; e < 8; ++e)
        v[e] = (short)Ts[(csq * 32 + j * 8 + e) * 136 + d];
      *(short8*)(dst + (size_t)d * SEQ + csq * 32 + j * 8) = v;
    }
  }
}

// ---------------- causal flash attention, bf16 ----------------
// grid (SEQ/128, B*H); 512 threads = 8 waves x 16 q-rows; KVB=64.
// K/V staged via global_load_lds with pre-swizzled SOURCE (rule 21):
// LDS linear dest; chunk c' of row r holds global chunk c'^(r&7).
__global__ __launch_bounds__(512) void attn_kernel(
    const unsigned short* __restrict__ Q, const unsigned short* __restrict__ Kk,
    const unsigned short* __restrict__ Vt, unsigned short* __restrict__ O) {
  const int qt = (int)gridDim.x - 1 - (int)blockIdx.x;  // big tiles first
  const int q0 = qt * 128;
  const int bh = blockIdx.y, b = bh >> 4, h = bh & 15;
  const size_t base = (size_t)b * SEQ * DMODEL + (size_t)h * HD;
  const unsigned short* vbase = Vt + ((size_t)bh << 18);

  __shared__ unsigned short Ks[64 * 128];    // [kv][128d], swizzled chunks
  __shared__ unsigned short Vs[128 * 64];    // [d][64kv],  swizzled chunks
  __shared__ unsigned short Pl[8 * 16 * 64]; // per-wave [16q][64kv], swizzled

  const int t = threadIdx.x, w = t >> 6, lane = t & 63;
  const int g = lane >> 4, cl = lane & 15;

  short8 qf[4];
  {
    const unsigned short* qrow = Q + base + (size_t)(q0 + w * 16 + cl) * DMODEL;
#pragma unroll
    for (int kk = 0; kk < 4; ++kk) qf[kk] = *(const short8*)(qrow + kk * 32 + g * 8);
  }

  f32x4 o_acc[8];
  const f32x4 zero = {0.f, 0.f, 0.f, 0.f};
#pragma unroll
  for (int n = 0; n < 8; ++n) o_acc[n] = zero;
  float m_run[4], l_run[4];
#pragma unroll
  for (int r = 0; r < 4; ++r) { m_run[r] = -INFINITY; l_run[r] = 0.f; }

  const int my_qmax = q0 + w * 16 + 15;
  const int ntiles = 2 * qt + 2;
  constexpr float SC = 0.08838834764831845f * 1.4426950408889634f;  // 1/sqrt(128)*log2e

  for (int tkv = 0; tkv < ntiles; ++tkv) {
    const int kv0 = tkv * 64;
    __syncthreads();
    // stage K (64x128 = 1024 16B-chunks) + V (128x64 = 1024 chunks): 2 each/thread
#pragma unroll
    for (int p = 0; p < 2; ++p) {
      int ck = p * 512 + t;
      int kr = ck >> 4, kc = ck & 15;
      int kcg = kc ^ (kr & 7);               // inverse-swizzled global chunk
      __builtin_amdgcn_global_load_lds(
          (const __attribute__((address_space(1))) void*)(Kk + base + (size_t)(kv0 + kr) * DMODEL + kcg * 8),
          (__attribute__((address_space(3))) void*)(&Ks[ck * 8]), 16, 0, 0);
      int vd = ck >> 3, vc = ck & 7;
      int vcg = vc ^ (vd & 7);
      __builtin_amdgcn_global_load_lds(
          (const __attribute__((address_space(1))) void*)(vbase + (size_t)vd * SEQ + kv0 + vcg * 8),
          (__attribute__((address_space(3))) void*)(&Vs[ck * 8]), 16, 0, 0);
    }
    __syncthreads();

    if (kv0 <= my_qmax) {
      // QK^T: S[q(16) x kv(64)] per wave
      float sm[4][4];
#pragma unroll
      for (int c = 0; c < 4; ++c) {
        f32x4 sa = zero;
#pragma unroll
        for (int kk = 0; kk < 4; ++kk) {
          short8 kf = *(const short8*)&Ks[(c * 16 + cl) * 128 + (((kk * 4 + g) ^ (cl & 7)) << 3)];
          sa = __builtin_amdgcn_mfma_f32_16x16x32_bf16(qf[kk], kf, sa, 0, 0, 0);
        }
#pragma unroll
        for (int r = 0; r < 4; ++r) {
          float sv = sa[r] * SC;
          int kvg = kv0 + c * 16 + cl;
          int qg  = q0 + w * 16 + g * 4 + r;
          sm[c][r] = (kvg > qg) ? -INFINITY : sv;
        }
      }
      // online softmax (per 16-lane group; rows = g*4+r)
      float alpha[4];
#pragma unroll
      for (int r = 0; r < 4; ++r) {
        float mx = fmaxf(fmaxf(sm[0][r], sm[1][r]), fmaxf(sm[2][r], sm[3][r]));
#pragma unroll
        for (int msk = 8; msk >= 1; msk >>= 1) mx = fmaxf(mx, __shfl_xor(mx, msk, 16));
        float mnew = fmaxf(m_run[r], mx);
        alpha[r] = exp2f(m_run[r] - mnew);
        m_run[r] = mnew;
        float s0 = 0.f;
#pragma unroll
        for (int c = 0; c < 4; ++c) {
          float p = exp2f(sm[c][r] - mnew);
          sm[c][r] = p;
          s0 += p;
        }
#pragma unroll
        for (int msk = 8; msk >= 1; msk >>= 1) s0 += __shfl_xor(s0, msk, 16);
        l_run[r] = l_run[r] * alpha[r] + s0;
      }
#pragma unroll
      for (int n = 0; n < 8; ++n)
#pragma unroll
        for (int r = 0; r < 4; ++r) o_acc[n][r] *= alpha[r];
      // P -> LDS (bf16), swizzled: row q, chunk = kv>>3 xor (q&7)
#pragma unroll
      for (int c = 0; c < 4; ++c)
#pragma unroll
        for (int r = 0; r < 4; ++r) {
          int q = g * 4 + r;
          int chs = ((c * 2 + (cl >> 3)) ^ (q & 7)) << 3;
          Pl[w * 1024 + q * 64 + chs + (cl & 7)] = f2bf(sm[c][r]);
        }
      // PV: out[q x hd] += P[q x kv] * V[kv x hd]
#pragma unroll
      for (int kk = 0; kk < 2; ++kk) {
        short8 pa = *(const short8*)&Pl[w * 1024 + cl * 64 + (((kk * 4 + g) ^ (cl & 7)) << 3)];
#pragma unroll
        for (int n = 0; n < 8; ++n) {
          short8 vf = *(const short8*)&Vs[(n * 16 + cl) * 64 + (((kk * 4 + g) ^ (cl & 7)) << 3)];
          o_acc[n] = __builtin_amdgcn_mfma_f32_16x16x32_bf16(pa, vf, o_acc[n], 0, 0, 0);
        }
      }
    }
  }
  // epilogue: O[q][hd] = acc / l
  {
    const size_t obase = base + (size_t)(q0 + w * 16) * DMODEL;
#pragma unroll
    for (int r = 0; r < 4; ++r) {
      float inv = 1.0f / l_run[r];
      int qrow = g * 4 + r;
#pragma unroll
      for (int n = 0; n < 8; ++n)
        O[obase + (size_t)qrow * DMODEL + n * 16 + cl] = f2bf(o_acc[n][r] * inv);
    }
  }
}

// ---------------- launch ----------------
extern "C" void kernel_launch(void* const* d_in, const int* in_sizes, int n_in,
                              void* d_out, int out_size, void* d_ws, size_t ws_size,
                              hipStream_t stream) {
  const float* x  = (const float*)d_in[0];
  const float* Wq = (const float*)d_in[1];
  const float* Wk = (const float*)d_in[2];
  const float* Wv = (const float*)d_in[3];
  const float* Wo = (const float*)d_in[4];
  float* out = (float*)d_out;

  unsigned short* wsb = (unsigned short*)d_ws;
  const size_t XN = (size_t)MROWS * DMODEL;      // 16,777,216
  const size_t WN = (size_t)DMODEL * DMODEL;     // 4,194,304
  unsigned short* xb  = wsb;                     // bf16 x; reused as Vt after QKV GEMM
  unsigned short* wqb = xb  + XN;
  unsigned short* wkb = wqb + WN;
  unsigned short* wvb = wkb + WN;
  unsigned short* wob = wvb + WN;
  unsigned short* qb  = wob + WN;
  unsigned short* kb  = qb  + XN;
  unsigned short* vb  = kb  + XN;
  unsigned short* aob = vb  + XN;
  float* cost = (float*)(aob + XN);
  float* sint = cost + (size_t)SEQ * 64;
  unsigned short* vtg = xb;                      // [bh][d][s], overlays xb (dead after GEMM)

  // 1. convert inputs to bf16
  cvt_f32_bf16<<<(int)(XN / 4 / 256), 256, 0, stream>>>(x,  xb,  (int)(XN / 4));
  cvt_f32_bf16<<<(int)(WN / 4 / 256), 256, 0, stream>>>(Wq, wqb, (int)(WN / 4));
  cvt_f32_bf16<<<(int)(WN / 4 / 256), 256, 0, stream>>>(Wk, wkb, (int)(WN / 4));
  cvt_f32_bf16<<<(int)(WN / 4 / 256), 256, 0, stream>>>(Wv, wvb, (int)(WN / 4));
  cvt_f32_bf16<<<(int)(WN / 4 / 256), 256, 0, stream>>>(Wo, wob, (int)(WN / 4));

  // 2. RoPE table
  rope_table<<<(SEQ * 64) / 256, 256, 0, stream>>>(cost, sint);

  // 3. QKV projections (fused launch via z)
  gemm_nt<true><<<dim3(MROWS / 128, DMODEL / 128, 3), 256, 0, stream>>>(
      xb, wqb, wkb, wvb, (void*)qb, (void*)kb, (void*)vb, DMODEL, DMODEL);

  // 4. V transpose (xb is dead now; vtg overlays it)
  transpose_v<<<dim3(SEQ / 128, BATCH * NHEADS), 256, 0, stream>>>(vb, vtg);

  // 5. RoPE on q, k
  rope_apply<<<(MROWS * NHEADS * 16) / 256, 256, 0, stream>>>(qb, cost, sint);
  rope_apply<<<(MROWS * NHEADS * 16) / 256, 256, 0, stream>>>(kb, cost, sint);

  // 6. causal flash attention
  attn_kernel<<<dim3(SEQ / 128, BATCH * NHEADS), 512, 0, stream>>>(qb, kb, vtg, aob);

  // 7. output projection (fp32 out)
  gemm_nt<false><<<dim3(MROWS / 128, DMODEL / 128, 1), 256, 0, stream>>>(
      aob, wob, wob, wob, (void*)out, (void*)out, (void*)out, DMODEL, DMODEL);
}